// Round 3
// baseline (91.277 us; speedup 1.0000x reference)
//
#include <hip/hip_runtime.h>
#include <hip/hip_bf16.h>

// Problem constants (fixed shapes from setup_inputs)
constexpr int NPTS = 16384;   // points per batch
constexpr int NCTR = 2048;    // centers per batch
constexpr int NCH  = 64;      // feature channels
constexpr int KK   = 32;      // neighbors per center
constexpr int NB   = 2;       // batches
// radius^2: reference compares d2 < fp32(0.04) (python double 0.2*0.2 -> f32)
#define R2 0.04f

// -------- Kernel 1 (prep): fused transpose + ball query --------
// blocks [0,512):   transpose features (b,64,16384) -> (b,16384,64) into ws
// blocks [512,1536): ball query, one wave per center; writes out_xyz + idx buf
// Fusing overlaps the scan's latency tails with transpose BW work.
__global__ __launch_bounds__(256) void prep_kernel(
    const float* __restrict__ points,   // (2,16384,3)
    const float* __restrict__ centers,  // (2,2048,3)
    const float* __restrict__ feats,    // (2,64,16384)
    float* __restrict__ featsT,         // ws: (2,16384,64)
    float* __restrict__ out_xyz,        // (2,3,2048,32)
    int* __restrict__ idx_out)          // ws: (4096,32)
{
#pragma clang fp contract(off)          // match numpy's step-rounded (no-FMA) d2 EXACTLY (R1: absmax=0)
    __shared__ float tile[64][65];      // transpose half (16.6 KB)
    __shared__ int   s_idx[4][KK];      // query half (512 B)

    if (blockIdx.x < 512) {
        // ---------------- transpose ----------------
        const int b  = blockIdx.x >> 8;
        const int n0 = (blockIdx.x & 255) * 64;
        const int t  = threadIdx.x;
        const int nl = t & 63;           // fast index (coalesced)
        const int q  = t >> 6;           // 0..3

        const float* fb = feats + (size_t)b * NCH * NPTS;
#pragma unroll
        for (int r = 0; r < 16; ++r) {
            int c = r * 4 + q;
            tile[c][nl] = fb[(size_t)c * NPTS + n0 + nl];
        }
        __syncthreads();
        float* ftb = featsT + ((size_t)b * NPTS + n0) * NCH;
#pragma unroll
        for (int r = 0; r < 16; ++r) {
            int n = r * 4 + q;
            ftb[(size_t)n * NCH + nl] = tile[nl][n];   // 2-way max (free)
        }
        return;
    }

    // ---------------- ball query: one wave per center ----------------
    const int wave = threadIdx.x >> 6;
    const int lane = threadIdx.x & 63;
    const int cg   = (blockIdx.x - 512) * 4 + wave;   // 0..4095
    const int b    = cg >> 11;                        // /2048
    const int g    = cg & (NCTR - 1);

    const float* pb = points + (size_t)b * NPTS * 3;
    const float* cc = centers + (size_t)cg * 3;
    const float cx = cc[0], cy = cc[1], cz = cc[2];
    const float c2 = (cx * cx + cy * cy) + cz * cz;

    int* idxs = s_idx[wave];

    // chunked ballot scan (512 pts/chunk), next chunk prefetched to registers
    float x[8], y[8], z[8], nx[8], ny[8], nz[8];
#pragma unroll
    for (int j = 0; j < 8; ++j) {
        const int i = j * 64 + lane;
        x[j] = pb[i * 3 + 0]; y[j] = pb[i * 3 + 1]; z[j] = pb[i * 3 + 2];
    }
    int cnt = 0;
    for (int base = 0; base < NPTS; base += 512) {
        const int nbb = (base + 512 < NPTS) ? base + 512 : 0;
#pragma unroll
        for (int j = 0; j < 8; ++j) {
            const int i = nbb + j * 64 + lane;
            nx[j] = pb[i * 3 + 0]; ny[j] = pb[i * 3 + 1]; nz[j] = pb[i * 3 + 2];
        }
#pragma unroll
        for (int j = 0; j < 8; ++j) {
            const float p2 = (x[j] * x[j] + y[j] * y[j]) + z[j] * z[j];
            const float cp = (cx * x[j] + cy * y[j]) + cz * z[j];
            const float d2 = (c2 + p2) - 2.0f * cp;
            const bool hit = d2 < R2;
            const unsigned long long m = __ballot(hit);
            if (hit) {
                const int slot = cnt + __popcll(m & ((1ull << lane) - 1ull));
                if (slot < KK) idxs[slot] = base + j * 64 + lane;
            }
            cnt += (int)__popcll(m);
        }
        if (cnt >= KK) break;                 // wave-uniform (cnt from ballot)
#pragma unroll
        for (int j = 0; j < 8; ++j) { x[j] = nx[j]; y[j] = ny[j]; z[j] = nz[j]; }
    }
    __syncthreads();              // LDS visibility (all 4 waves reach once)

    // pad + write idx and grouped_xyz
    const int cpd = cnt < KK ? cnt : KK;
    const int first = (cnt > 0) ? idxs[0] : 0;
    if (lane < KK) {
        const int id = (lane < cpd) ? idxs[lane] : first;
        idx_out[cg * KK + lane] = id;
        const float px = pb[id * 3 + 0];
        const float py = pb[id * 3 + 1];
        const float pz = pb[id * 3 + 2];
        const size_t ob = (((size_t)b * 3 + 0) * NCTR + g) * KK + lane;
        out_xyz[ob + (size_t)0 * NCTR * KK] = (px - cx) / 0.2f;
        out_xyz[ob + (size_t)1 * NCTR * KK] = (py - cy) / 0.2f;
        out_xyz[ob + (size_t)2 * NCTR * KK] = (pz - cz) / 0.2f;
    }
}

// -------- Kernel 2: feature grouping. One block (4 waves) per center. --------
// Gather: float4 row loads (256B/row coalesced), LDS transpose, float4 stores
// (128B contiguous per 8 lanes). 8.8 KB LDS -> 8 blocks/CU (100% occupancy).
__global__ __launch_bounds__(256) void group_feats(
    const float* __restrict__ featsT,   // (2,16384,64)
    const int* __restrict__ idx_in,     // (4096,32)
    float* __restrict__ out_feat)       // (2,64,2048,32)
{
    __shared__ float sf[KK][68];        // stride 68: 16B-aligned rows for b128
    __shared__ int   ids[KK];

    const int t  = threadIdx.x;
    const int cg = blockIdx.x;          // 0..4095
    const int b  = cg >> 11;
    const int g  = cg & (NCTR - 1);

    if (t < KK) ids[t] = idx_in[cg * KK + t];
    __syncthreads();

    // gather: wave w handles rows 8w..8w+7; 4 rows per b128 instruction
    const int wave = t >> 6, lane = t & 63;
    const int li = lane & 15, r = lane >> 4;
    const float* ftb = featsT + (size_t)b * NPTS * NCH;
#pragma unroll
    for (int i = 0; i < 2; ++i) {
        const int k = wave * 8 + i * 4 + r;
        const float4 v = *((const float4*)(ftb + (size_t)ids[k] * NCH) + li);
        *(float4*)&sf[k][4 * li] = v;   // byte addr 4*(68k+4li): 16B aligned
    }
    __syncthreads();

    // write: thread owns k-quad [4kq,4kq+4) of channel c; 2 channels/thread
    const int kq = t & 7;
    const int cL = t >> 3;              // 0..31
    const size_t ob = ((size_t)b * NCH * NCTR + g) * KK;
#pragma unroll
    for (int p = 0; p < 2; ++p) {
        const int c = cL + 32 * p;
        float4 v;
        v.x = sf[4 * kq + 0][c];        // 4-way bank conflict here: ~negligible
        v.y = sf[4 * kq + 1][c];
        v.z = sf[4 * kq + 2][c];
        v.w = sf[4 * kq + 3][c];
        *(float4*)(out_feat + ob + (size_t)c * NCTR * KK + 4 * kq) = v;
    }
}

// -------- Fallback: R2 fused kernel (used only if ws is too small) --------
__global__ __launch_bounds__(256) void ballquery_group(
    const float* __restrict__ points, const float* __restrict__ centers,
    const float* __restrict__ feats, float* __restrict__ out_xyz,
    float* __restrict__ out_feat)
{
#pragma clang fp contract(off)
    __shared__ int   s_idx[4][KK];
    __shared__ float s_f[4][KK][65];
    const int wave = threadIdx.x >> 6, lane = threadIdx.x & 63;
    const int cg = blockIdx.x * 4 + wave;
    const int b = cg >> 11, g = cg & (NCTR - 1);
    const float* pb = points + (size_t)b * NPTS * 3;
    const float* cc = centers + (size_t)cg * 3;
    const float cx = cc[0], cy = cc[1], cz = cc[2];
    const float c2 = (cx * cx + cy * cy) + cz * cz;
    int* idxs = s_idx[wave];
    int cnt = 0;
    for (int base = 0; base < NPTS; base += 64) {
        const int i = base + lane;
        const float px = pb[i * 3 + 0], py = pb[i * 3 + 1], pz = pb[i * 3 + 2];
        const float p2 = (px * px + py * py) + pz * pz;
        const float cp = (cx * px + cy * py) + cz * pz;
        const float d2 = (c2 + p2) - 2.0f * cp;
        const bool hit = d2 < R2;
        const unsigned long long m = __ballot(hit);
        if (hit) {
            const int slot = cnt + __popcll(m & ((1ull << lane) - 1ull));
            if (slot < KK) idxs[slot] = i;
        }
        cnt += (int)__popcll(m);
        if (cnt >= KK) break;
    }
    __syncthreads();
    const int cpd = cnt < KK ? cnt : KK;
    const int first = (cnt > 0) ? idxs[0] : 0;
    if (lane < KK) idxs[lane] = (lane < cpd) ? idxs[lane] : first;
    __syncthreads();
    if (lane < KK) {
        const int id = idxs[lane];
        const float px = pb[id * 3 + 0], py = pb[id * 3 + 1], pz = pb[id * 3 + 2];
        const size_t ob = (((size_t)b * 3 + 0) * NCTR + g) * KK + lane;
        out_xyz[ob + (size_t)0 * NCTR * KK] = (px - cx) / 0.2f;
        out_xyz[ob + (size_t)1 * NCTR * KK] = (py - cy) / 0.2f;
        out_xyz[ob + (size_t)2 * NCTR * KK] = (pz - cz) / 0.2f;
    }
    float (*sf)[65] = s_f[wave];
    const float* fb = feats + (size_t)b * NCH * NPTS;
    for (int k = 0; k < KK; ++k) {
        const int id = idxs[k];
        sf[k][lane] = fb[(size_t)lane * NPTS + id];
    }
    __syncthreads();
    const int k = lane & 31, ch = lane >> 5;
    const size_t ob = ((size_t)b * NCH * NCTR + g) * KK;
#pragma unroll
    for (int cc2 = 0; cc2 < 32; ++cc2) {
        const int c = cc2 * 2 + ch;
        out_feat[ob + (size_t)c * NCTR * KK + k] = sf[k][c];
    }
}

extern "C" void kernel_launch(void* const* d_in, const int* in_sizes, int n_in,
                              void* d_out, int out_size, void* d_ws, size_t ws_size,
                              hipStream_t stream) {
    const float* points  = (const float*)d_in[0];   // (2,16384,3)
    const float* centers = (const float*)d_in[1];   // (2,2048,3)
    const float* feats   = (const float*)d_in[2];   // (2,64,16384)

    float* out      = (float*)d_out;
    float* out_xyz  = out;                                    // (2,3,2048,32)
    float* out_feat = out + (size_t)NB * 3 * NCTR * KK;       // (2,64,2048,32)

    const size_t ftBytes  = (size_t)NB * NPTS * NCH * sizeof(float);
    const size_t idxBytes = (size_t)NB * NCTR * KK * sizeof(int);

    if (ws_size >= ftBytes + idxBytes) {
        float* featsT = (float*)d_ws;
        int*   idxbuf = (int*)((char*)d_ws + ftBytes);
        // blocks [0,512): transpose; [512,1536): query (4096 centers, 4/block)
        prep_kernel<<<1536, 256, 0, stream>>>(points, centers, feats,
                                              featsT, out_xyz, idxbuf);
        group_feats<<<NB * NCTR, 256, 0, stream>>>(featsT, idxbuf, out_feat);
    } else {
        ballquery_group<<<(NB * NCTR) / 4, 256, 0, stream>>>(
            points, centers, feats, out_xyz, out_feat);
    }
}

// Round 4
// 86.225 us; speedup vs baseline: 1.0586x; 1.0586x over previous
//
#include <hip/hip_runtime.h>
#include <hip/hip_bf16.h>

// Problem constants (fixed shapes from setup_inputs)
constexpr int NPTS = 16384;   // points per batch
constexpr int NCTR = 2048;    // centers per batch
constexpr int NCH  = 64;      // feature channels
constexpr int KK   = 32;      // neighbors per center
constexpr int NB   = 2;       // batches
// radius^2: reference compares d2 < fp32(0.04) (python double 0.2*0.2 -> f32)
#define R2 0.04f

// -------- Kernel A (prep): transpose feats + pack points --------
// blocks [0,512):   transpose features (b,64,16384) -> (b,16384,64) into ws
// blocks [512,544): pack points -> float4 (x,y,z,p2) into ws
// p2 computed ONCE here with the exact R1-verified formula (contract off),
// so the scan's d2 stays bit-identical to numpy.
__global__ __launch_bounds__(256) void prep_kernel(
    const float* __restrict__ points,   // (2,16384,3)
    const float* __restrict__ feats,    // (2,64,16384)
    float* __restrict__ featsT,         // ws: (2,16384,64)
    float4* __restrict__ packed)        // ws: (2*16384) {x,y,z,p2}
{
#pragma clang fp contract(off)
    __shared__ float tile[64][65];      // +1 pad: conflict-free transpose

    if (blockIdx.x < 512) {
        // ---------------- transpose ----------------
        const int b  = blockIdx.x >> 8;
        const int n0 = (blockIdx.x & 255) * 64;
        const int t  = threadIdx.x;
        const int nl = t & 63;
        const int q  = t >> 6;

        const float* fb = feats + (size_t)b * NCH * NPTS;
#pragma unroll
        for (int r = 0; r < 16; ++r) {
            int c = r * 4 + q;
            tile[c][nl] = fb[(size_t)c * NPTS + n0 + nl];
        }
        __syncthreads();
        float* ftb = featsT + ((size_t)b * NPTS + n0) * NCH;
#pragma unroll
        for (int r = 0; r < 16; ++r) {
            int n = r * 4 + q;
            ftb[(size_t)n * NCH + nl] = tile[nl][n];   // 2-way max (free)
        }
        return;
    }

    // ---------------- pack: 32 blocks x 256 thr x 4 pts ----------------
    const int tid = (blockIdx.x - 512) * 256 + threadIdx.x;  // 0..8191
#pragma unroll
    for (int s = 0; s < 4; ++s) {
        const int i = tid + s * 8192;                        // 0..32767 (b*NPTS+n)
        const float x = points[3 * i + 0];
        const float y = points[3 * i + 1];
        const float z = points[3 * i + 2];
        const float p2 = (x * x + y * y) + z * z;            // exact R1 formula
        packed[i] = make_float4(x, y, z, p2);
    }
}

// -------- Kernel B: fused ball query + grouping. One wave per center. ----
// Fused (R2 shape): fast centers' gathers hide under slow centers' scan
// tails (R3's split kernel serialized on the slowest tail -> regressed).
// Scan reads packed float4 (1 dwordx4/lane per 64 pts vs 3 strided dwords).
__global__ __launch_bounds__(256, 4) void query_group(
    const float4* __restrict__ packed,  // (2,16384) {x,y,z,p2}
    const float* __restrict__ centers,  // (2,2048,3)
    const float* __restrict__ featsT,   // (2,16384,64)
    float* __restrict__ out_xyz,        // (2,3,2048,32)
    float* __restrict__ out_feat)       // (2,64,2048,32)
{
#pragma clang fp contract(off)          // keep numpy-exact d2 (absmax=0 since R1)
    __shared__ int   s_idx[4][KK];
    __shared__ float s_f[4][KK][68];    // stride 68: 16B-aligned rows for b128

    const int wave = threadIdx.x >> 6;
    const int lane = threadIdx.x & 63;
    const int cg   = blockIdx.x * 4 + wave;   // 0..4095
    const int b    = cg >> 11;
    const int g    = cg & (NCTR - 1);

    const float4* pk = packed + (size_t)b * NPTS;
    const float* cc = centers + (size_t)cg * 3;
    const float cx = cc[0], cy = cc[1], cz = cc[2];
    const float c2 = (cx * cx + cy * cy) + cz * cz;

    int* idxs = s_idx[wave];

    // ---- chunked ballot scan: 512 pts/chunk, next chunk prefetched ----
    float4 cur[8], nxt[8];
#pragma unroll
    for (int j = 0; j < 8; ++j) cur[j] = pk[j * 64 + lane];
    int cnt = 0;
    for (int base = 0; base < NPTS; base += 512) {
        const int nbb = (base + 512 < NPTS) ? base + 512 : 0;
#pragma unroll
        for (int j = 0; j < 8; ++j) nxt[j] = pk[nbb + j * 64 + lane];
#pragma unroll
        for (int j = 0; j < 8; ++j) {
            const float4 v = cur[j];
            const float cp = (cx * v.x + cy * v.y) + cz * v.z;
            const float d2 = (c2 + v.w) - 2.0f * cp;
            const bool hit = d2 < R2;
            const unsigned long long m = __ballot(hit);
            if (hit) {
                const int slot = cnt + __popcll(m & ((1ull << lane) - 1ull));
                if (slot < KK) idxs[slot] = base + j * 64 + lane;
            }
            cnt += (int)__popcll(m);
        }
        if (cnt >= KK) break;                 // wave-uniform (cnt from ballot)
#pragma unroll
        for (int j = 0; j < 8; ++j) cur[j] = nxt[j];
    }
    __syncthreads();              // LDS visibility (all 4 waves reach once)

    // ---- pad + grouped_xyz ----
    const int cpd = cnt < KK ? cnt : KK;
    const int first = (cnt > 0) ? idxs[0] : 0;
    if (lane < KK) {
        const int id = (lane < cpd) ? idxs[lane] : first;
        idxs[lane] = id;
        const float4 v = pk[id];
        const size_t ob = (((size_t)b * 3 + 0) * NCTR + g) * KK + lane;
        out_xyz[ob + (size_t)0 * NCTR * KK] = (v.x - cx) / 0.2f;
        out_xyz[ob + (size_t)1 * NCTR * KK] = (v.y - cy) / 0.2f;
        out_xyz[ob + (size_t)2 * NCTR * KK] = (v.z - cz) / 0.2f;
    }
    __syncthreads();

    // ---- gather: 4 rows per b128 instr; 8 instrs cover 32 rows ----
    float (*sf)[68] = s_f[wave];
    const int li = lane & 15, r = lane >> 4;
    const float* ftb = featsT + (size_t)b * NPTS * NCH;
#pragma unroll
    for (int i = 0; i < 8; ++i) {
        const int k = i * 4 + r;
        const float4 v = *((const float4*)(ftb + (size_t)idxs[k] * NCH) + li);
        *(float4*)&sf[k][4 * li] = v;   // (17k+li)%8 float4-slots: 2-way (free)
    }
    __syncthreads();

    // ---- write: lane owns k-quad [4kq,4kq+4) of channel c; 8 ch passes ----
    const int kq = lane & 7;
    const int c0 = lane >> 3;           // 0..7
    const size_t ob = ((size_t)b * NCH * NCTR + g) * KK;
#pragma unroll
    for (int p = 0; p < 8; ++p) {
        const int c = c0 + 8 * p;
        float4 v;
        v.x = sf[4 * kq + 0][c];        // 4-way LDS conflict: ~negligible here
        v.y = sf[4 * kq + 1][c];
        v.z = sf[4 * kq + 2][c];
        v.w = sf[4 * kq + 3][c];
        *(float4*)(out_feat + ob + (size_t)c * NCTR * KK + 4 * kq) = v;
    }
}

// -------- Fallback: R2 fused kernel (used only if ws is too small) --------
__global__ __launch_bounds__(256) void ballquery_group(
    const float* __restrict__ points, const float* __restrict__ centers,
    const float* __restrict__ feats, float* __restrict__ out_xyz,
    float* __restrict__ out_feat)
{
#pragma clang fp contract(off)
    __shared__ int   s_idx[4][KK];
    __shared__ float s_f[4][KK][65];
    const int wave = threadIdx.x >> 6, lane = threadIdx.x & 63;
    const int cg = blockIdx.x * 4 + wave;
    const int b = cg >> 11, g = cg & (NCTR - 1);
    const float* pb = points + (size_t)b * NPTS * 3;
    const float* cc = centers + (size_t)cg * 3;
    const float cx = cc[0], cy = cc[1], cz = cc[2];
    const float c2 = (cx * cx + cy * cy) + cz * cz;
    int* idxs = s_idx[wave];
    int cnt = 0;
    for (int base = 0; base < NPTS; base += 64) {
        const int i = base + lane;
        const float px = pb[i * 3 + 0], py = pb[i * 3 + 1], pz = pb[i * 3 + 2];
        const float p2 = (px * px + py * py) + pz * pz;
        const float cp = (cx * px + cy * py) + cz * pz;
        const float d2 = (c2 + p2) - 2.0f * cp;
        const bool hit = d2 < R2;
        const unsigned long long m = __ballot(hit);
        if (hit) {
            const int slot = cnt + __popcll(m & ((1ull << lane) - 1ull));
            if (slot < KK) idxs[slot] = i;
        }
        cnt += (int)__popcll(m);
        if (cnt >= KK) break;
    }
    __syncthreads();
    const int cpd = cnt < KK ? cnt : KK;
    const int first = (cnt > 0) ? idxs[0] : 0;
    if (lane < KK) idxs[lane] = (lane < cpd) ? idxs[lane] : first;
    __syncthreads();
    if (lane < KK) {
        const int id = idxs[lane];
        const float px = pb[id * 3 + 0], py = pb[id * 3 + 1], pz = pb[id * 3 + 2];
        const size_t ob = (((size_t)b * 3 + 0) * NCTR + g) * KK + lane;
        out_xyz[ob + (size_t)0 * NCTR * KK] = (px - cx) / 0.2f;
        out_xyz[ob + (size_t)1 * NCTR * KK] = (py - cy) / 0.2f;
        out_xyz[ob + (size_t)2 * NCTR * KK] = (pz - cz) / 0.2f;
    }
    float (*sf)[65] = s_f[wave];
    const float* fb = feats + (size_t)b * NCH * NPTS;
    for (int k = 0; k < KK; ++k) {
        const int id = idxs[k];
        sf[k][lane] = fb[(size_t)lane * NPTS + id];
    }
    __syncthreads();
    const int k = lane & 31, ch = lane >> 5;
    const size_t ob = ((size_t)b * NCH * NCTR + g) * KK;
#pragma unroll
    for (int cc2 = 0; cc2 < 32; ++cc2) {
        const int c = cc2 * 2 + ch;
        out_feat[ob + (size_t)c * NCTR * KK + k] = sf[k][c];
    }
}

extern "C" void kernel_launch(void* const* d_in, const int* in_sizes, int n_in,
                              void* d_out, int out_size, void* d_ws, size_t ws_size,
                              hipStream_t stream) {
    const float* points  = (const float*)d_in[0];   // (2,16384,3)
    const float* centers = (const float*)d_in[1];   // (2,2048,3)
    const float* feats   = (const float*)d_in[2];   // (2,64,16384)

    float* out      = (float*)d_out;
    float* out_xyz  = out;                                    // (2,3,2048,32)
    float* out_feat = out + (size_t)NB * 3 * NCTR * KK;       // (2,64,2048,32)

    const size_t ftBytes = (size_t)NB * NPTS * NCH * sizeof(float);   // 8 MB
    const size_t pkBytes = (size_t)NB * NPTS * 4 * sizeof(float);     // 512 KB

    if (ws_size >= ftBytes + pkBytes) {
        float*  featsT = (float*)d_ws;
        float4* packed = (float4*)((char*)d_ws + ftBytes);
        // blocks [0,512): transpose; [512,544): pack points
        prep_kernel<<<544, 256, 0, stream>>>(points, feats, featsT, packed);
        // 4096 centers, 4 per block (one wave each)
        query_group<<<(NB * NCTR) / 4, 256, 0, stream>>>(
            packed, centers, featsT, out_xyz, out_feat);
    } else {
        ballquery_group<<<(NB * NCTR) / 4, 256, 0, stream>>>(
            points, centers, feats, out_xyz, out_feat);
    }
}